// Round 6
// baseline (54.911 us; speedup 1.0000x reference)
//
#include <hip/hip_runtime.h>

// SparseInnerProductDecoder: out[e] = sigmoid(dot(z[row[e]], z[col[e]])), d=64.
//
// R5: R3 structure exactly (fp16 z in d_ws, 8 lanes x 16B = 128B row gathers,
// f32 accumulate, xor-tree reduce, 1 edge per group, normal cached stores)
// plus ONE change: nontemporal hint on the single-use index-stream loads so
// the 10MB index stream doesn't evict the hot 12.8MB fp16 z set from the
// 4MB/XCD L2s. (R4's regression traced to nt scattered stores + unroll;
// both reverted.)

typedef _Float16 half8 __attribute__((ext_vector_type(8)));
typedef float    f32x4 __attribute__((ext_vector_type(4)));

__global__ __launch_bounds__(256) void convert_f32_to_f16_kernel(
    const float* __restrict__ z, _Float16* __restrict__ zh, int n /* floats, %8==0 */)
{
    int i = blockIdx.x * blockDim.x + threadIdx.x;   // one thread per 8 floats
    if (i * 8 >= n) return;
    const f32x4* src = reinterpret_cast<const f32x4*>(z) + (size_t)i * 2;
    f32x4 f0 = __builtin_nontemporal_load(src);       // z f32 read exactly once
    f32x4 f1 = __builtin_nontemporal_load(src + 1);
    half8 h;
    h[0] = (_Float16)f0[0]; h[1] = (_Float16)f0[1];
    h[2] = (_Float16)f0[2]; h[3] = (_Float16)f0[3];
    h[4] = (_Float16)f1[0]; h[5] = (_Float16)f1[1];
    h[6] = (_Float16)f1[2]; h[7] = (_Float16)f1[3];
    reinterpret_cast<half8*>(zh)[i] = h;               // normal store: warms L2
}

// 8 lanes per edge: 8 x 16B = 128B = one fp16 z row = one cache line.
__global__ __launch_bounds__(256) void sipd_f16_kernel(
    const _Float16* __restrict__ zh,
    const int* __restrict__ row,
    const int* __restrict__ col,
    float* __restrict__ out,
    int E)
{
    int tid = blockIdx.x * blockDim.x + threadIdx.x;
    int e = tid >> 3;
    int l = tid & 7;
    if (e >= E) return;

    int r = __builtin_nontemporal_load(row + e);   // single-use stream: don't cache
    int c = __builtin_nontemporal_load(col + e);

    half8 a = reinterpret_cast<const half8*>(zh + (size_t)r * 64)[l];
    half8 b = reinterpret_cast<const half8*>(zh + (size_t)c * 64)[l];

    float t = (float)a[0] * (float)b[0];
#pragma unroll
    for (int i = 1; i < 8; ++i)
        t = fmaf((float)a[i], (float)b[i], t);

    t += __shfl_xor(t, 1);
    t += __shfl_xor(t, 2);
    t += __shfl_xor(t, 4);

    if (l == 0) {
        out[e] = 1.0f / (1.0f + __expf(-t));   // normal store: L2 write-combines
    }
}

// Fallback (ws too small): f32 path, 16 lanes/edge.
__global__ __launch_bounds__(256) void sipd_f32_kernel(
    const float* __restrict__ z,
    const int* __restrict__ row,
    const int* __restrict__ col,
    float* __restrict__ out,
    int E)
{
    int tid = blockIdx.x * blockDim.x + threadIdx.x;
    int e = tid >> 4;
    int l = tid & 15;
    if (e >= E) return;
    int r = row[e];
    int c = col[e];
    const f32x4* zr = reinterpret_cast<const f32x4*>(z + (size_t)r * 64);
    const f32x4* zc = reinterpret_cast<const f32x4*>(z + (size_t)c * 64);
    f32x4 a = zr[l];
    f32x4 b = zc[l];
    float t = a[0] * b[0];
    t = fmaf(a[1], b[1], t); t = fmaf(a[2], b[2], t); t = fmaf(a[3], b[3], t);
    t += __shfl_xor(t, 1); t += __shfl_xor(t, 2);
    t += __shfl_xor(t, 4); t += __shfl_xor(t, 8);
    if (l == 0) out[e] = 1.0f / (1.0f + __expf(-t));
}

extern "C" void kernel_launch(void* const* d_in, const int* in_sizes, int n_in,
                              void* d_out, int out_size, void* d_ws, size_t ws_size,
                              hipStream_t stream)
{
    const float* z   = (const float*)d_in[0];
    const int*   ei  = (const int*)d_in[1];   // [2, E] flat: row block then col block
    float*       out = (float*)d_out;

    int E   = out_size;        // 1,250,000
    int n_z = in_sizes[0];     // 100000 * 64 = 6,400,000 floats
    const int* row = ei;
    const int* col = ei + E;

    size_t zh_bytes = (size_t)n_z * sizeof(_Float16);   // 12.8 MB

    if (ws_size >= zh_bytes) {
        _Float16* zh = (_Float16*)d_ws;

        int nvec = n_z / 8;
        convert_f32_to_f16_kernel<<<(nvec + 255) / 256, 256, 0, stream>>>(z, zh, n_z);

        const int block = 256;                 // 32 edges per block
        int grid = (E + 31) / 32;
        sipd_f16_kernel<<<grid, block, 0, stream>>>(zh, row, col, out, E);
    } else {
        const int block = 256;
        int grid = (E + 15) / 16;
        sipd_f32_kernel<<<grid, block, 0, stream>>>(z, row, col, out, E);
    }
}

// Round 7
// 48.436 us; speedup vs baseline: 1.1337x; 1.1337x over previous
//
#include <hip/hip_runtime.h>

// SparseInnerProductDecoder: out[e] = sigmoid(dot(z[row[e]], z[col[e]])), d=64.
//
// R6: exact revert to R3 (best measured: 48.5us). Both nt-hint experiments
// (R4b: nt scattered stores + unroll; R5: nt index loads) regressed —
// nt bypasses L2 allocation, fragmenting the index stream into per-wave
// fabric requests on the already-saturated L2-fill path.
//
// Structure: convert z to fp16 in d_ws (~6.5us, streaming-bound), then
// gather 128B fp16 rows (8 lanes x 16B = one cache line), f32 accumulate,
// xor-tree reduce, lane 0 writes sigmoid. Gather runs at the ~3.5TB/s
// random-128B-line L2-fill ceiling (z=12.8MB >> 4MB/XCD L2, L3-resident).

typedef _Float16 half8 __attribute__((ext_vector_type(8)));
typedef float    f32x4 __attribute__((ext_vector_type(4)));

__global__ __launch_bounds__(256) void convert_f32_to_f16_kernel(
    const float* __restrict__ z, _Float16* __restrict__ zh, int n /* floats, %8==0 */)
{
    int i = blockIdx.x * blockDim.x + threadIdx.x;   // one thread per 8 floats
    if (i * 8 >= n) return;
    const f32x4* src = reinterpret_cast<const f32x4*>(z) + (size_t)i * 2;
    f32x4 f0 = src[0];
    f32x4 f1 = src[1];
    half8 h;
    h[0] = (_Float16)f0[0]; h[1] = (_Float16)f0[1];
    h[2] = (_Float16)f0[2]; h[3] = (_Float16)f0[3];
    h[4] = (_Float16)f1[0]; h[5] = (_Float16)f1[1];
    h[6] = (_Float16)f1[2]; h[7] = (_Float16)f1[3];
    reinterpret_cast<half8*>(zh)[i] = h;
}

// 8 lanes per edge: 8 x 16B = 128B = one fp16 z row = one cache line.
__global__ __launch_bounds__(256) void sipd_f16_kernel(
    const _Float16* __restrict__ zh,
    const int* __restrict__ row,
    const int* __restrict__ col,
    float* __restrict__ out,
    int E)
{
    int tid = blockIdx.x * blockDim.x + threadIdx.x;
    int e = tid >> 3;
    int l = tid & 7;
    if (e >= E) return;

    int r = row[e];
    int c = col[e];

    half8 a = reinterpret_cast<const half8*>(zh + (size_t)r * 64)[l];
    half8 b = reinterpret_cast<const half8*>(zh + (size_t)c * 64)[l];

    float t = (float)a[0] * (float)b[0];
#pragma unroll
    for (int i = 1; i < 8; ++i)
        t = fmaf((float)a[i], (float)b[i], t);

    t += __shfl_xor(t, 1);
    t += __shfl_xor(t, 2);
    t += __shfl_xor(t, 4);

    if (l == 0) {
        out[e] = 1.0f / (1.0f + __expf(-t));
    }
}

// Fallback (ws too small): f32 path, 16 lanes/edge.
__global__ __launch_bounds__(256) void sipd_f32_kernel(
    const float* __restrict__ z,
    const int* __restrict__ row,
    const int* __restrict__ col,
    float* __restrict__ out,
    int E)
{
    int tid = blockIdx.x * blockDim.x + threadIdx.x;
    int e = tid >> 4;
    int l = tid & 15;
    if (e >= E) return;
    int r = row[e];
    int c = col[e];
    const f32x4* zr = reinterpret_cast<const f32x4*>(z + (size_t)r * 64);
    const f32x4* zc = reinterpret_cast<const f32x4*>(z + (size_t)c * 64);
    f32x4 a = zr[l];
    f32x4 b = zc[l];
    float t = a[0] * b[0];
    t = fmaf(a[1], b[1], t); t = fmaf(a[2], b[2], t); t = fmaf(a[3], b[3], t);
    t += __shfl_xor(t, 1); t += __shfl_xor(t, 2);
    t += __shfl_xor(t, 4); t += __shfl_xor(t, 8);
    if (l == 0) out[e] = 1.0f / (1.0f + __expf(-t));
}

extern "C" void kernel_launch(void* const* d_in, const int* in_sizes, int n_in,
                              void* d_out, int out_size, void* d_ws, size_t ws_size,
                              hipStream_t stream)
{
    const float* z   = (const float*)d_in[0];
    const int*   ei  = (const int*)d_in[1];   // [2, E] flat: row block then col block
    float*       out = (float*)d_out;

    int E   = out_size;        // 1,250,000
    int n_z = in_sizes[0];     // 100000 * 64 = 6,400,000 floats
    const int* row = ei;
    const int* col = ei + E;

    size_t zh_bytes = (size_t)n_z * sizeof(_Float16);   // 12.8 MB

    if (ws_size >= zh_bytes) {
        _Float16* zh = (_Float16*)d_ws;

        int nvec = n_z / 8;
        convert_f32_to_f16_kernel<<<(nvec + 255) / 256, 256, 0, stream>>>(z, zh, n_z);

        const int block = 256;                 // 32 edges per block
        int grid = (E + 31) / 32;
        sipd_f16_kernel<<<grid, block, 0, stream>>>(zh, row, col, out, E);
    } else {
        const int block = 256;
        int grid = (E + 15) / 16;
        sipd_f32_kernel<<<grid, block, 0, stream>>>(z, row, col, out, E);
    }
}